// Round 1
// baseline (1841.821 us; speedup 1.0000x reference)
//
#include <hip/hip_runtime.h>
#include <hip/hip_bf16.h>
#include <math.h>

#define C_    128
#define T_    16
#define HW_   256
#define N_    4096
#define HID_  256
#define MLPH_ 512
#define HEADS_ 8
#define DH_   32
#define SCALE_ 0.17677669529663689f  // 32^-0.5

// ---------------- K1: fusion MLP  (x,frame) -> xs[b][n][c], n = hw*16 + t ----
__global__ __launch_bounds__(256) void k_fusion(
    const float* __restrict__ x, const float* __restrict__ fidx,
    const float* __restrict__ w1, const float* __restrict__ b1,
    const float* __restrict__ w2, const float* __restrict__ b2,
    float* __restrict__ xs) {
  __shared__ float in[129];
  __shared__ float hid[512];
  int bid = blockIdx.x;                 // b*4096 + t*256 + hw
  int b = bid >> 12, t = (bid >> 8) & 15, hw = bid & 255;
  int tid = threadIdx.x;
  if (tid < 128) in[tid] = x[((b * 128 + tid) * 16 + t) * 256 + hw];
  if (tid == 128) in[128] = fidx[t];
  __syncthreads();
  for (int jj = 0; jj < 2; ++jj) {
    int j = tid + jj * 256;
    float acc = b1[j];
    for (int i = 0; i < 129; ++i) acc = fmaf(in[i], w1[i * 512 + j], acc);
    hid[j] = 0.5f * acc * (1.0f + erff(acc * 0.70710678118654752f));
  }
  __syncthreads();
  if (tid < 128) {
    float acc = b2[tid];
    for (int j = 0; j < 512; ++j) acc = fmaf(hid[j], w2[j * 128 + tid], acc);
    int n = hw * 16 + t;
    xs[((size_t)b * N_ + n) * C_ + tid] = acc;
  }
}

// ---------------- K2: LN + QKV projections ----------------------------------
__global__ __launch_bounds__(256) void k_ln_qkv(
    const float* __restrict__ xs, const float* __restrict__ g,
    const float* __restrict__ bt, const float* __restrict__ wq,
    const float* __restrict__ wk, const float* __restrict__ wv,
    float* __restrict__ q, float* __restrict__ k, float* __restrict__ v) {
  __shared__ float row[128];
  __shared__ float xn[128];
  __shared__ float stats[2];
  int bn = blockIdx.x;                  // b*4096 + n
  int tid = threadIdx.x;
  if (tid < 128) row[tid] = xs[(size_t)bn * C_ + tid];
  __syncthreads();
  if (tid < 64) {
    float s = row[tid] + row[tid + 64];
    #pragma unroll
    for (int off = 32; off; off >>= 1) s += __shfl_down(s, off);
    if (tid == 0) stats[0] = s * (1.0f / 128.0f);
  }
  __syncthreads();
  float mean = stats[0];
  if (tid < 64) {
    float a = row[tid] - mean, c2 = row[tid + 64] - mean;
    float s = a * a + c2 * c2;
    #pragma unroll
    for (int off = 32; off; off >>= 1) s += __shfl_down(s, off);
    if (tid == 0) stats[1] = rsqrtf(s * (1.0f / 128.0f) + 1e-5f);
  }
  __syncthreads();
  float rstd = stats[1];
  if (tid < 128) xn[tid] = (row[tid] - mean) * rstd * g[tid] + bt[tid];
  __syncthreads();
  float aq = 0.f, ak = 0.f, av = 0.f;
  for (int i = 0; i < 128; ++i) {
    float xi = xn[i];
    aq = fmaf(xi, wq[i * 256 + tid], aq);
    ak = fmaf(xi, wk[i * 256 + tid], ak);
    av = fmaf(xi, wv[i * 256 + tid], av);
  }
  int b = bn >> 12, n = bn & 4095;
  int h = tid >> 5, d = tid & 31;
  size_t idx = ((size_t)((b * 8 + h) * N_ + n)) * DH_ + d;
  q[idx] = aq; k[idx] = ak; v[idx] = av;
}

// ---------------- K3: flash-style attention, thread-per-query ---------------
__global__ __launch_bounds__(256) void k_attn(
    const float* __restrict__ q, const float* __restrict__ k,
    const float* __restrict__ v, float* __restrict__ o) {
  __shared__ float kt[128 * 32];
  __shared__ float vt[128 * 32];
  int bh = blockIdx.x >> 4;             // b*8+h  in [0,16)
  int qb = blockIdx.x & 15;
  int n = qb * 256 + threadIdx.x;
  const float* qp = q + ((size_t)bh * N_ + n) * DH_;
  float qr[32];
  #pragma unroll
  for (int d = 0; d < 32; ++d) qr[d] = qp[d] * SCALE_;
  float m = -1e30f, l = 0.0f;
  float acc[32];
  #pragma unroll
  for (int d = 0; d < 32; ++d) acc[d] = 0.0f;
  const float* kb = k + (size_t)bh * N_ * DH_;
  const float* vb = v + (size_t)bh * N_ * DH_;
  for (int tile = 0; tile < 32; ++tile) {
    __syncthreads();
    const float4* ks = (const float4*)(kb + (size_t)tile * 128 * 32);
    const float4* vs = (const float4*)(vb + (size_t)tile * 128 * 32);
    float4* kd = (float4*)kt; float4* vd = (float4*)vt;
    #pragma unroll
    for (int u = 0; u < 4; ++u) {
      kd[threadIdx.x + u * 256] = ks[threadIdx.x + u * 256];
      vd[threadIdx.x + u * 256] = vs[threadIdx.x + u * 256];
    }
    __syncthreads();
    for (int j = 0; j < 128; ++j) {
      const float* kr = kt + j * 32;
      float s = 0.f;
      #pragma unroll
      for (int d = 0; d < 32; ++d) s = fmaf(qr[d], kr[d], s);
      const float* vr = vt + j * 32;
      bool upd = s > m;
      if (__any(upd)) {
        float mn = fmaxf(m, s);
        float corr = __expf(m - mn);
        float p = __expf(s - mn);
        l = l * corr + p;
        #pragma unroll
        for (int d = 0; d < 32; ++d) acc[d] = fmaf(acc[d], corr, p * vr[d]);
        m = mn;
      } else {
        float p = __expf(s - m);
        l += p;
        #pragma unroll
        for (int d = 0; d < 32; ++d) acc[d] = fmaf(p, vr[d], acc[d]);
      }
    }
  }
  float inv = 1.0f / l;
  float* op = o + ((size_t)bh * N_ + n) * DH_;
  #pragma unroll
  for (int d = 0; d < 32; ++d) op[d] = acc[d] * inv;
}

// ---------------- K4: O projection + residual -------------------------------
__global__ __launch_bounds__(128) void k_oproj(
    const float* __restrict__ o, const float* __restrict__ wo,
    const float* __restrict__ bo, float* __restrict__ xs) {
  __shared__ float orow[256];
  int bn = blockIdx.x; int tid = threadIdx.x;
  int b = bn >> 12, n = bn & 4095;
  orow[tid] = o[((size_t)((b * 8 + (tid >> 5)) * N_ + n)) * DH_ + (tid & 31)];
  int t2 = tid + 128;
  orow[t2] = o[((size_t)((b * 8 + (t2 >> 5)) * N_ + n)) * DH_ + (t2 & 31)];
  __syncthreads();
  float acc = bo[tid];
  for (int j = 0; j < 256; ++j) acc = fmaf(orow[j], wo[j * 128 + tid], acc);
  xs[(size_t)bn * C_ + tid] += acc;
}

// ---------------- K5: LN + MLP + residual (in-place on xs) ------------------
__global__ __launch_bounds__(256) void k_mlp(
    float* __restrict__ xs, const float* __restrict__ g,
    const float* __restrict__ bt, const float* __restrict__ w1,
    const float* __restrict__ b1, const float* __restrict__ w2,
    const float* __restrict__ b2) {
  __shared__ float row[128];
  __shared__ float xn[128];
  __shared__ float hid[512];
  __shared__ float stats[2];
  int bn = blockIdx.x, tid = threadIdx.x;
  if (tid < 128) row[tid] = xs[(size_t)bn * C_ + tid];
  __syncthreads();
  if (tid < 64) {
    float s = row[tid] + row[tid + 64];
    #pragma unroll
    for (int off = 32; off; off >>= 1) s += __shfl_down(s, off);
    if (tid == 0) stats[0] = s * (1.0f / 128.0f);
  }
  __syncthreads();
  float mean = stats[0];
  if (tid < 64) {
    float a = row[tid] - mean, c2 = row[tid + 64] - mean;
    float s = a * a + c2 * c2;
    #pragma unroll
    for (int off = 32; off; off >>= 1) s += __shfl_down(s, off);
    if (tid == 0) stats[1] = rsqrtf(s * (1.0f / 128.0f) + 1e-5f);
  }
  __syncthreads();
  float rstd = stats[1];
  if (tid < 128) xn[tid] = (row[tid] - mean) * rstd * g[tid] + bt[tid];
  __syncthreads();
  for (int jj = 0; jj < 2; ++jj) {
    int j = tid + jj * 256;
    float acc = b1[j];
    for (int i = 0; i < 128; ++i) acc = fmaf(xn[i], w1[i * 512 + j], acc);
    hid[j] = 0.5f * acc * (1.0f + erff(acc * 0.70710678118654752f));
  }
  __syncthreads();
  if (tid < 128) {
    float acc = b2[tid];
    for (int j = 0; j < 512; ++j) acc = fmaf(hid[j], w2[j * 128 + tid], acc);
    xs[(size_t)bn * C_ + tid] = row[tid] + acc;
  }
}

// ---------------- K6: final transpose to (B,C,T,H,W) ------------------------
__global__ __launch_bounds__(256) void k_out(
    const float* __restrict__ xs, float* __restrict__ out) {
  int idx = blockIdx.x * 256 + threadIdx.x;   // b*524288 + c*4096 + t*256 + hw
  int hw = idx & 255;
  int t = (idx >> 8) & 15;
  int c = (idx >> 12) & 127;
  int b = idx >> 19;
  out[idx] = xs[((size_t)(b * N_ + hw * 16 + t)) * C_ + c];
}

extern "C" void kernel_launch(void* const* d_in, const int* in_sizes, int n_in,
                              void* d_out, int out_size, void* d_ws, size_t ws_size,
                              hipStream_t stream) {
  const float* x    = (const float*)d_in[0];
  const float* fidx = (const float*)d_in[1];
  const float* fw1  = (const float*)d_in[2];
  const float* fb1  = (const float*)d_in[3];
  const float* fw2  = (const float*)d_in[4];
  const float* fb2  = (const float*)d_in[5];
  const float* ag   = (const float*)d_in[6];
  const float* ab   = (const float*)d_in[7];
  const float* wq   = (const float*)d_in[8];
  const float* wk   = (const float*)d_in[9];
  const float* wv   = (const float*)d_in[10];
  const float* wo   = (const float*)d_in[11];
  const float* bo   = (const float*)d_in[12];
  const float* ng   = (const float*)d_in[13];
  const float* nb   = (const float*)d_in[14];
  const float* mw1  = (const float*)d_in[15];
  const float* mb1  = (const float*)d_in[16];
  const float* mw2  = (const float*)d_in[17];
  const float* mb2  = (const float*)d_in[18];
  float* out = (float*)d_out;
  float* ws  = (float*)d_ws;

  float* xs = ws;                        // 1,048,576
  float* q  = ws + 1048576;              // 2,097,152
  float* k  = q + 2097152;
  float* v  = k + 2097152;
  float* o  = v + 2097152;               // total 9,437,184 floats = 36 MiB

  k_fusion<<<8192, 256, 0, stream>>>(x, fidx, fw1, fb1, fw2, fb2, xs);
  k_ln_qkv<<<8192, 256, 0, stream>>>(xs, ag, ab, wq, wk, wv, q, k, v);
  k_attn  <<<256, 256, 0, stream>>>(q, k, v, o);
  k_oproj <<<8192, 128, 0, stream>>>(o, wo, bo, xs);
  k_mlp   <<<8192, 256, 0, stream>>>(xs, ng, nb, mw1, mb1, mw2, mb2);
  k_out   <<<4096, 256, 0, stream>>>(xs, out);
}

// Round 3
// 688.580 us; speedup vs baseline: 2.6748x; 2.6748x over previous
//
#include <hip/hip_runtime.h>
#include <hip/hip_bf16.h>
#include <math.h>

#define C_    128
#define T_    16
#define HW_   256
#define N_    4096
#define HID_  256
#define MLPH_ 512
#define HEADS_ 8
#define DH_   32
#define SCALE_ 0.17677669529663689f  // 32^-0.5

typedef __attribute__((ext_vector_type(8))) short short8;
typedef __attribute__((ext_vector_type(4))) float f32x4;

__device__ inline ushort f2bf(float x) {
  return __bfloat16_as_ushort(__float2bfloat16(x));
}

// ---------------- K1: fusion MLP  (x,frame) -> xs[b][n][c], n = hw*16 + t ----
__global__ __launch_bounds__(256) void k_fusion(
    const float* __restrict__ x, const float* __restrict__ fidx,
    const float* __restrict__ w1, const float* __restrict__ b1,
    const float* __restrict__ w2, const float* __restrict__ b2,
    float* __restrict__ xs) {
  __shared__ float in[129];
  __shared__ float hid[512];
  int bid = blockIdx.x;                 // b*4096 + t*256 + hw
  int b = bid >> 12, t = (bid >> 8) & 15, hw = bid & 255;
  int tid = threadIdx.x;
  if (tid < 128) in[tid] = x[((b * 128 + tid) * 16 + t) * 256 + hw];
  if (tid == 128) in[128] = fidx[t];
  __syncthreads();
  for (int jj = 0; jj < 2; ++jj) {
    int j = tid + jj * 256;
    float acc = b1[j];
    for (int i = 0; i < 129; ++i) acc = fmaf(in[i], w1[i * 512 + j], acc);
    hid[j] = 0.5f * acc * (1.0f + erff(acc * 0.70710678118654752f));
  }
  __syncthreads();
  if (tid < 128) {
    float acc = b2[tid];
    for (int j = 0; j < 512; ++j) acc = fmaf(hid[j], w2[j * 128 + tid], acc);
    int n = hw * 16 + t;
    xs[((size_t)b * N_ + n) * C_ + tid] = acc;
  }
}

// ---------------- K2: LN + QKV projections -> bf16 Q(scaled), K, V^T --------
__global__ __launch_bounds__(256) void k_ln_qkv(
    const float* __restrict__ xs, const float* __restrict__ g,
    const float* __restrict__ bt, const float* __restrict__ wq,
    const float* __restrict__ wk, const float* __restrict__ wv,
    ushort* __restrict__ qg, ushort* __restrict__ kg, ushort* __restrict__ vtg) {
  __shared__ float row[128];
  __shared__ float xn[128];
  __shared__ float stats[2];
  int bn = blockIdx.x;                  // b*4096 + n
  int tid = threadIdx.x;
  if (tid < 128) row[tid] = xs[(size_t)bn * C_ + tid];
  __syncthreads();
  if (tid < 64) {
    float s = row[tid] + row[tid + 64];
    #pragma unroll
    for (int off = 32; off; off >>= 1) s += __shfl_down(s, off);
    if (tid == 0) stats[0] = s * (1.0f / 128.0f);
  }
  __syncthreads();
  float mean = stats[0];
  if (tid < 64) {
    float a = row[tid] - mean, c2 = row[tid + 64] - mean;
    float s = a * a + c2 * c2;
    #pragma unroll
    for (int off = 32; off; off >>= 1) s += __shfl_down(s, off);
    if (tid == 0) stats[1] = rsqrtf(s * (1.0f / 128.0f) + 1e-5f);
  }
  __syncthreads();
  float rstd = stats[1];
  if (tid < 128) xn[tid] = (row[tid] - mean) * rstd * g[tid] + bt[tid];
  __syncthreads();
  float aq = 0.f, ak = 0.f, av = 0.f;
  for (int i = 0; i < 128; ++i) {
    float xi = xn[i];
    aq = fmaf(xi, wq[i * 256 + tid], aq);
    ak = fmaf(xi, wk[i * 256 + tid], ak);
    av = fmaf(xi, wv[i * 256 + tid], av);
  }
  int b = bn >> 12, n = bn & 4095;
  int h = tid >> 5, d = tid & 31;
  int bh = b * 8 + h;
  qg[((size_t)bh * N_ + n) * 32 + d] = f2bf(aq * SCALE_);
  kg[((size_t)bh * N_ + n) * 32 + d] = f2bf(ak);
  vtg[((size_t)bh * 32 + d) * (size_t)N_ + n] = f2bf(av);
}

// ---------------- K3: MFMA flash attention (swapped-operand, no LDS) --------
// Per wave: 16 queries. S^T = mfma(K_tile, Q^T) so lane holds P^T values that
// feed the PV mfma B-operand directly (key-permuted QK tiles -> zero shuffles).
// O^T accumulated in-register; V stored transposed [bh][32][N].
__global__ __launch_bounds__(256, 4) void k_attn(
    const ushort* __restrict__ qg, const ushort* __restrict__ kg,
    const ushort* __restrict__ vtg, float* __restrict__ o) {
  int tid = threadIdx.x;
  int lane = tid & 63, wid = tid >> 6;
  int q_ = lane & 15, g = lane >> 4;
  int orig = blockIdx.x;
  // XCD swizzle: 1024 blocks = 8 XCD * 128; contiguous chunk per XCD -> 2 heads/XCD
  int lin = ((orig & 7) << 7) + (orig >> 3);
  int bh = lin >> 6, qb = lin & 63;
  int qbase = qb * 64 + wid * 16;

  short8 qf = *(const short8*)(qg + ((size_t)bh * N_ + qbase + q_) * 32 + g * 8);

  const ushort* Kb = kg + (size_t)bh * N_ * 32;
  const ushort* Vb = vtg + (size_t)bh * 32 * (size_t)N_;
  // row permutation within each QK tile: tile s covers key base(s)+8g+r,
  // base(s) = 32*(s>>1) + 4*(s&1); A-row m=q_ loads key base(s)+rp
  int rp = (q_ & 3) + ((q_ >> 2) << 3);

  float m = -1e30f, l = 0.f;
  f32x4 ot0 = {0.f, 0.f, 0.f, 0.f};
  f32x4 ot1 = {0.f, 0.f, 0.f, 0.f};
  const f32x4 zz = {0.f, 0.f, 0.f, 0.f};

  for (int kt = 0; kt < 64; ++kt) {
    int kofs = kt * 64;
    // K fragments (coalesced 16B/lane), permuted rows
    short8 kf0 = *(const short8*)(Kb + (size_t)(kofs + 0  + rp) * 32 + g * 8);
    short8 kf1 = *(const short8*)(Kb + (size_t)(kofs + 4  + rp) * 32 + g * 8);
    short8 kf2 = *(const short8*)(Kb + (size_t)(kofs + 32 + rp) * 32 + g * 8);
    short8 kf3 = *(const short8*)(Kb + (size_t)(kofs + 36 + rp) * 32 + g * 8);
    // V^T fragments for this key chunk (issue early; rows d, cols key)
    short8 v00 = *(const short8*)(Vb + (size_t)(q_)      * N_ + kofs      + (g << 3));
    short8 v01 = *(const short8*)(Vb + (size_t)(16 + q_) * N_ + kofs      + (g << 3));
    short8 v10 = *(const short8*)(Vb + (size_t)(q_)      * N_ + kofs + 32 + (g << 3));
    short8 v11 = *(const short8*)(Vb + (size_t)(16 + q_) * N_ + kofs + 32 + (g << 3));

    f32x4 s0 = __builtin_amdgcn_mfma_f32_16x16x32_bf16(kf0, qf, zz, 0, 0, 0);
    f32x4 s1 = __builtin_amdgcn_mfma_f32_16x16x32_bf16(kf1, qf, zz, 0, 0, 0);
    f32x4 s2 = __builtin_amdgcn_mfma_f32_16x16x32_bf16(kf2, qf, zz, 0, 0, 0);
    f32x4 s3 = __builtin_amdgcn_mfma_f32_16x16x32_bf16(kf3, qf, zz, 0, 0, 0);

    // ---- online softmax over the 64-key chunk (per query column q_) ----
    float p[16];
    #pragma unroll
    for (int r = 0; r < 4; ++r) {
      p[r]      = s0[r];
      p[4 + r]  = s1[r];
      p[8 + r]  = s2[r];
      p[12 + r] = s3[r];
    }
    float pmax = p[0];
    #pragma unroll
    for (int i = 1; i < 16; ++i) pmax = fmaxf(pmax, p[i]);
    pmax = fmaxf(pmax, __shfl_xor(pmax, 16, 64));
    pmax = fmaxf(pmax, __shfl_xor(pmax, 32, 64));
    float mn = fmaxf(m, pmax);
    float corr = __expf(m - mn);
    m = mn;
    float lsum = 0.f;
    #pragma unroll
    for (int i = 0; i < 16; ++i) { p[i] = __expf(p[i] - mn); lsum += p[i]; }
    lsum += __shfl_xor(lsum, 16, 64);
    lsum += __shfl_xor(lsum, 32, 64);
    l = l * corr + lsum;
    #pragma unroll
    for (int r = 0; r < 4; ++r) { ot0[r] *= corr; ot1[r] *= corr; }

    // P^T fragments: in-lane thanks to the key permutation
    short8 b0, b1;
    #pragma unroll
    for (int i = 0; i < 8; ++i) {
      b0[i] = (short)f2bf(p[i]);
      b1[i] = (short)f2bf(p[8 + i]);
    }
    ot0 = __builtin_amdgcn_mfma_f32_16x16x32_bf16(v00, b0, ot0, 0, 0, 0);
    ot1 = __builtin_amdgcn_mfma_f32_16x16x32_bf16(v01, b0, ot1, 0, 0, 0);
    ot0 = __builtin_amdgcn_mfma_f32_16x16x32_bf16(v10, b1, ot0, 0, 0, 0);
    ot1 = __builtin_amdgcn_mfma_f32_16x16x32_bf16(v11, b1, ot1, 0, 0, 0);
  }

  float inv = 1.0f / l;
  float* op = o + ((size_t)bh * N_ + qbase + q_) * 32;
  #pragma unroll
  for (int r = 0; r < 4; ++r) {
    op[(g << 2) + r]      = ot0[r] * inv;
    op[16 + (g << 2) + r] = ot1[r] * inv;
  }
}

// ---------------- K4: O projection + residual -------------------------------
__global__ __launch_bounds__(128) void k_oproj(
    const float* __restrict__ o, const float* __restrict__ wo,
    const float* __restrict__ bo, float* __restrict__ xs) {
  __shared__ float orow[256];
  int bn = blockIdx.x; int tid = threadIdx.x;
  int b = bn >> 12, n = bn & 4095;
  orow[tid] = o[((size_t)((b * 8 + (tid >> 5)) * N_ + n)) * DH_ + (tid & 31)];
  int t2 = tid + 128;
  orow[t2] = o[((size_t)((b * 8 + (t2 >> 5)) * N_ + n)) * DH_ + (t2 & 31)];
  __syncthreads();
  float acc = bo[tid];
  for (int j = 0; j < 256; ++j) acc = fmaf(orow[j], wo[j * 128 + tid], acc);
  xs[(size_t)bn * C_ + tid] += acc;
}

// ---------------- K5: LN + MLP + residual (in-place on xs) ------------------
__global__ __launch_bounds__(256) void k_mlp(
    float* __restrict__ xs, const float* __restrict__ g,
    const float* __restrict__ bt, const float* __restrict__ w1,
    const float* __restrict__ b1, const float* __restrict__ w2,
    const float* __restrict__ b2) {
  __shared__ float row[128];
  __shared__ float xn[128];
  __shared__ float hid[512];
  __shared__ float stats[2];
  int bn = blockIdx.x, tid = threadIdx.x;
  if (tid < 128) row[tid] = xs[(size_t)bn * C_ + tid];
  __syncthreads();
  if (tid < 64) {
    float s = row[tid] + row[tid + 64];
    #pragma unroll
    for (int off = 32; off; off >>= 1) s += __shfl_down(s, off);
    if (tid == 0) stats[0] = s * (1.0f / 128.0f);
  }
  __syncthreads();
  float mean = stats[0];
  if (tid < 64) {
    float a = row[tid] - mean, c2 = row[tid + 64] - mean;
    float s = a * a + c2 * c2;
    #pragma unroll
    for (int off = 32; off; off >>= 1) s += __shfl_down(s, off);
    if (tid == 0) stats[1] = rsqrtf(s * (1.0f / 128.0f) + 1e-5f);
  }
  __syncthreads();
  float rstd = stats[1];
  if (tid < 128) xn[tid] = (row[tid] - mean) * rstd * g[tid] + bt[tid];
  __syncthreads();
  for (int jj = 0; jj < 2; ++jj) {
    int j = tid + jj * 256;
    float acc = b1[j];
    for (int i = 0; i < 128; ++i) acc = fmaf(xn[i], w1[i * 512 + j], acc);
    hid[j] = 0.5f * acc * (1.0f + erff(acc * 0.70710678118654752f));
  }
  __syncthreads();
  if (tid < 128) {
    float acc = b2[tid];
    for (int j = 0; j < 512; ++j) acc = fmaf(hid[j], w2[j * 128 + tid], acc);
    xs[(size_t)bn * C_ + tid] = row[tid] + acc;
  }
}

// ---------------- K6: final transpose to (B,C,T,H,W) ------------------------
__global__ __launch_bounds__(256) void k_out(
    const float* __restrict__ xs, float* __restrict__ out) {
  int idx = blockIdx.x * 256 + threadIdx.x;   // b*524288 + c*4096 + t*256 + hw
  int hw = idx & 255;
  int t = (idx >> 8) & 15;
  int c = (idx >> 12) & 127;
  int b = idx >> 19;
  out[idx] = xs[((size_t)(b * N_ + hw * 16 + t)) * C_ + c];
}

extern "C" void kernel_launch(void* const* d_in, const int* in_sizes, int n_in,
                              void* d_out, int out_size, void* d_ws, size_t ws_size,
                              hipStream_t stream) {
  const float* x    = (const float*)d_in[0];
  const float* fidx = (const float*)d_in[1];
  const float* fw1  = (const float*)d_in[2];
  const float* fb1  = (const float*)d_in[3];
  const float* fw2  = (const float*)d_in[4];
  const float* fb2  = (const float*)d_in[5];
  const float* ag   = (const float*)d_in[6];
  const float* ab   = (const float*)d_in[7];
  const float* wq   = (const float*)d_in[8];
  const float* wk   = (const float*)d_in[9];
  const float* wv   = (const float*)d_in[10];
  const float* wo   = (const float*)d_in[11];
  const float* bo   = (const float*)d_in[12];
  const float* ng   = (const float*)d_in[13];
  const float* nb   = (const float*)d_in[14];
  const float* mw1  = (const float*)d_in[15];
  const float* mb1  = (const float*)d_in[16];
  const float* mw2  = (const float*)d_in[17];
  const float* mb2  = (const float*)d_in[18];
  float* out = (float*)d_out;

  char* base = (char*)d_ws;
  float*  xs = (float*)  base;                      // 4 MiB
  ushort* qb = (ushort*) (base + (4  << 20));       // 4 MiB (bf16)
  ushort* kb = (ushort*) (base + (8  << 20));       // 4 MiB
  ushort* vt = (ushort*) (base + (12 << 20));       // 4 MiB (V^T)
  float*  o  = (float*)  (base + (16 << 20));       // 8 MiB -> 24 MiB total

  k_fusion<<<8192, 256, 0, stream>>>(x, fidx, fw1, fb1, fw2, fb2, xs);
  k_ln_qkv<<<8192, 256, 0, stream>>>(xs, ag, ab, wq, wk, wv, qb, kb, vt);
  k_attn  <<<1024, 256, 0, stream>>>(qb, kb, vt, o);
  k_oproj <<<8192, 128, 0, stream>>>(o, wo, bo, xs);
  k_mlp   <<<8192, 256, 0, stream>>>(xs, ng, nb, mw1, mb1, mw2, mb2);
  k_out   <<<4096, 256, 0, stream>>>(xs, out);
}

// Round 5
// 384.833 us; speedup vs baseline: 4.7860x; 1.7893x over previous
//
#include <hip/hip_runtime.h>
#include <hip/hip_bf16.h>
#include <math.h>

#define N_    4096

typedef __attribute__((ext_vector_type(8))) short short8;
typedef __attribute__((ext_vector_type(4))) float f32x4;

__device__ inline ushort f2bf(float x) {
  return __bfloat16_as_ushort(__float2bfloat16(x));
}

// ============ K0: weight prep -> bf16 transposed layouts =====================
// w1t_f[512][128], w2t_f[128][512], wqkvt[768][128] (q rows pre-scaled by
// 1/sqrt(32)*log2e), wot[128][256], w1t_m[512][128], w2t_m[128][512], w1fr[512]
__global__ __launch_bounds__(256) void k_prep(
    const float* __restrict__ fw1, const float* __restrict__ fw2,
    const float* __restrict__ wq, const float* __restrict__ wk,
    const float* __restrict__ wv, const float* __restrict__ wo,
    const float* __restrict__ mw1, const float* __restrict__ mw2,
    ushort* __restrict__ w1t_f, ushort* __restrict__ w2t_f,
    ushort* __restrict__ wqkvt, ushort* __restrict__ wot,
    ushort* __restrict__ w1t_m, ushort* __restrict__ w2t_m,
    float* __restrict__ w1fr) {
  int idx = blockIdx.x * 256 + threadIdx.x;
  const float SL2E = (float)(0.17677669529663689 * 1.4426950408889634);
  if (idx < 65536) { int n = idx >> 7, k = idx & 127; w1t_f[idx] = f2bf(fw1[k * 512 + n]); return; }
  idx -= 65536;
  if (idx < 65536) { int n = idx >> 9, k = idx & 511; w2t_f[idx] = f2bf(fw2[k * 128 + n]); return; }
  idx -= 65536;
  if (idx < 98304) {
    int n = idx >> 7, k = idx & 127;
    float v = (n < 256) ? wq[k * 256 + n] * SL2E
            : (n < 512) ? wk[k * 256 + (n - 256)]
                        : wv[k * 256 + (n - 512)];
    wqkvt[idx] = f2bf(v); return;
  }
  idx -= 98304;
  if (idx < 32768) { int n = idx >> 8, k = idx & 255; wot[idx] = f2bf(wo[k * 128 + n]); return; }
  idx -= 32768;
  if (idx < 65536) { int n = idx >> 7, k = idx & 127; w1t_m[idx] = f2bf(mw1[k * 512 + n]); return; }
  idx -= 65536;
  if (idx < 65536) { int n = idx >> 9, k = idx & 511; w2t_m[idx] = f2bf(mw2[k * 128 + n]); return; }
  idx -= 65536;
  if (idx < 512) w1fr[idx] = fw1[128 * 512 + idx];
}

// ============ K1: fusion GEMM1: x(+frame) @ W1 -> GELU -> hf bf16 ===========
// token_f = b*4096 + t*256 + hw ; M=8192,K=128,N=512; frame col via acc init.
__global__ __launch_bounds__(64) void k_fusion1(
    const float* __restrict__ x, const float* __restrict__ fidx,
    const ushort* __restrict__ w1t, const float* __restrict__ w1fr,
    const float* __restrict__ b1, ushort* __restrict__ hf) {
  int l = threadIdx.x; int m15 = l & 15, g = l >> 4;
  int tf0 = blockIdx.x * 16;
  int c0 = blockIdx.y * 128 + m15;
  float fe = fidx[(tf0 >> 8) & 15];
  int tfA = tf0 + m15;
  const float* xb = x + (((size_t)(tfA >> 12) * 2048 + ((tfA >> 8) & 15)) * 256 + (tfA & 255));
  f32x4 acc[8];
  #pragma unroll
  for (int nt = 0; nt < 8; ++nt) {
    float init = b1[c0 + nt * 16] + fe * w1fr[c0 + nt * 16];
    acc[nt] = (f32x4){init, init, init, init};
  }
  #pragma unroll
  for (int ks = 0; ks < 4; ++ks) {
    short8 af;
    #pragma unroll
    for (int j = 0; j < 8; ++j)
      af[j] = (short)f2bf(xb[(size_t)(ks * 32 + g * 8 + j) * 4096]);
    #pragma unroll
    for (int nt = 0; nt < 8; ++nt) {
      short8 bfr = *(const short8*)(w1t + (size_t)(c0 + nt * 16) * 128 + ks * 32 + g * 8);
      acc[nt] = __builtin_amdgcn_mfma_f32_16x16x32_bf16(af, bfr, acc[nt], 0, 0, 0);
    }
  }
  #pragma unroll
  for (int nt = 0; nt < 8; ++nt) {
    int c = c0 + nt * 16;
    #pragma unroll
    for (int r = 0; r < 4; ++r) {
      float v = acc[nt][r];
      v = 0.5f * v * (1.0f + erff(v * 0.70710678118654752f));
      hf[(size_t)(tf0 + 4 * g + r) * 512 + c] = f2bf(v);
    }
  }
}

// ============ K2: fusion GEMM2 + bias + LN epilogue -> xs f32, xsn bf16 =====
// reorders token_f -> token_s = b*4096 + hw*16 + t
__global__ __launch_bounds__(64) void k_fusion2(
    const ushort* __restrict__ hf, const ushort* __restrict__ w2t,
    const float* __restrict__ b2, const float* __restrict__ lng,
    const float* __restrict__ lnb, float* __restrict__ xs,
    ushort* __restrict__ xsn) {
  int l = threadIdx.x; int m15 = l & 15, g = l >> 4;
  int tf0 = blockIdx.x * 16;
  f32x4 acc[8];
  #pragma unroll
  for (int nt = 0; nt < 8; ++nt) {
    float init = b2[nt * 16 + m15];
    acc[nt] = (f32x4){init, init, init, init};
  }
  const ushort* ha = hf + (size_t)(tf0 + m15) * 512;
  #pragma unroll 4
  for (int ks = 0; ks < 16; ++ks) {
    short8 af = *(const short8*)(ha + ks * 32 + g * 8);
    #pragma unroll
    for (int nt = 0; nt < 8; ++nt) {
      short8 bfr = *(const short8*)(w2t + (size_t)(nt * 16 + m15) * 512 + ks * 32 + g * 8);
      acc[nt] = __builtin_amdgcn_mfma_f32_16x16x32_bf16(af, bfr, acc[nt], 0, 0, 0);
    }
  }
  float sum[4] = {0.f, 0.f, 0.f, 0.f}, ssq[4] = {0.f, 0.f, 0.f, 0.f};
  #pragma unroll
  for (int nt = 0; nt < 8; ++nt)
    #pragma unroll
    for (int r = 0; r < 4; ++r) { float v = acc[nt][r]; sum[r] += v; ssq[r] += v * v; }
  #pragma unroll
  for (int mask = 1; mask < 16; mask <<= 1)
    #pragma unroll
    for (int r = 0; r < 4; ++r) {
      sum[r] += __shfl_xor(sum[r], mask, 64);
      ssq[r] += __shfl_xor(ssq[r], mask, 64);
    }
  float mean[4], rstd[4]; int ts[4];
  #pragma unroll
  for (int r = 0; r < 4; ++r) {
    mean[r] = sum[r] * (1.0f / 128.0f);
    float var = ssq[r] * (1.0f / 128.0f) - mean[r] * mean[r];
    rstd[r] = rsqrtf(var + 1e-5f);
    int tf = tf0 + 4 * g + r;
    ts[r] = (tf >> 12) * 4096 + (tf & 255) * 16 + ((tf >> 8) & 15);
  }
  #pragma unroll
  for (int nt = 0; nt < 8; ++nt) {
    int c = nt * 16 + m15;
    float ga = lng[c], be = lnb[c];
    #pragma unroll
    for (int r = 0; r < 4; ++r) {
      float v = acc[nt][r];
      xs[(size_t)ts[r] * 128 + c] = v;
      xsn[(size_t)ts[r] * 128 + c] = f2bf((v - mean[r]) * rstd[r] * ga + be);
    }
  }
}

// ============ K3: QKV GEMM: xsn @ [wq|wk|wv]^T -> qg, kg, vt ================
__global__ __launch_bounds__(64) void k_qkv(
    const ushort* __restrict__ xsn, const ushort* __restrict__ wqkvt,
    ushort* __restrict__ qg, ushort* __restrict__ kg, ushort* __restrict__ vt) {
  int l = threadIdx.x; int m15 = l & 15, g = l >> 4;
  int ts0 = blockIdx.x * 16;
  int c0 = blockIdx.y * 128 + m15;
  f32x4 acc[8];
  #pragma unroll
  for (int nt = 0; nt < 8; ++nt) acc[nt] = (f32x4){0.f, 0.f, 0.f, 0.f};
  const ushort* xa = xsn + (size_t)(ts0 + m15) * 128;
  #pragma unroll
  for (int ks = 0; ks < 4; ++ks) {
    short8 af = *(const short8*)(xa + ks * 32 + g * 8);
    #pragma unroll
    for (int nt = 0; nt < 8; ++nt) {
      short8 bfr = *(const short8*)(wqkvt + (size_t)(c0 + nt * 16) * 128 + ks * 32 + g * 8);
      acc[nt] = __builtin_amdgcn_mfma_f32_16x16x32_bf16(af, bfr, acc[nt], 0, 0, 0);
    }
  }
  int b = ts0 >> 12;
  #pragma unroll
  for (int nt = 0; nt < 8; ++nt) {
    int c = c0 + nt * 16;
    #pragma unroll
    for (int r = 0; r < 4; ++r) {
      int n = (ts0 + 4 * g + r) & 4095;
      float v = acc[nt][r];
      if (c < 256) {
        qg[((size_t)(b * 8 + (c >> 5)) * N_ + n) * 32 + (c & 31)] = f2bf(v);
      } else if (c < 512) {
        int cc = c - 256;
        kg[((size_t)(b * 8 + (cc >> 5)) * N_ + n) * 32 + (cc & 31)] = f2bf(v);
      } else {
        int cc = c - 512;
        vt[((size_t)(b * 8 + (cc >> 5)) * 32 + (cc & 31)) * (size_t)N_ + n] = f2bf(v);
      }
    }
  }
}

// ============ K4: MFMA flash attention (unchanged structure; exp2, bf16 out) =
__global__ __launch_bounds__(256, 4) void k_attn(
    const ushort* __restrict__ qg, const ushort* __restrict__ kg,
    const ushort* __restrict__ vtg, ushort* __restrict__ ob) {
  int tid = threadIdx.x;
  int lane = tid & 63, wid = tid >> 6;
  int q_ = lane & 15, g = lane >> 4;
  int orig = blockIdx.x;
  int lin = ((orig & 7) << 7) + (orig >> 3);
  int bh = lin >> 6, qb = lin & 63;
  int qbase = qb * 64 + wid * 16;

  short8 qf = *(const short8*)(qg + ((size_t)bh * N_ + qbase + q_) * 32 + g * 8);

  const ushort* Kb = kg + (size_t)bh * N_ * 32;
  const ushort* Vb = vtg + (size_t)bh * 32 * (size_t)N_;
  int rp = (q_ & 3) + ((q_ >> 2) << 3);

  float m = -1e30f, l = 0.f;
  f32x4 ot0 = {0.f, 0.f, 0.f, 0.f};
  f32x4 ot1 = {0.f, 0.f, 0.f, 0.f};
  const f32x4 zz = {0.f, 0.f, 0.f, 0.f};

  for (int kt = 0; kt < 64; ++kt) {
    int kofs = kt * 64;
    short8 kf0 = *(const short8*)(Kb + (size_t)(kofs + 0  + rp) * 32 + g * 8);
    short8 kf1 = *(const short8*)(Kb + (size_t)(kofs + 4  + rp) * 32 + g * 8);
    short8 kf2 = *(const short8*)(Kb + (size_t)(kofs + 32 + rp) * 32 + g * 8);
    short8 kf3 = *(const short8*)(Kb + (size_t)(kofs + 36 + rp) * 32 + g * 8);
    short8 v00 = *(const short8*)(Vb + (size_t)(q_)      * N_ + kofs      + (g << 3));
    short8 v01 = *(const short8*)(Vb + (size_t)(16 + q_) * N_ + kofs      + (g << 3));
    short8 v10 = *(const short8*)(Vb + (size_t)(q_)      * N_ + kofs + 32 + (g << 3));
    short8 v11 = *(const short8*)(Vb + (size_t)(16 + q_) * N_ + kofs + 32 + (g << 3));

    f32x4 s0 = __builtin_amdgcn_mfma_f32_16x16x32_bf16(kf0, qf, zz, 0, 0, 0);
    f32x4 s1 = __builtin_amdgcn_mfma_f32_16x16x32_bf16(kf1, qf, zz, 0, 0, 0);
    f32x4 s2 = __builtin_amdgcn_mfma_f32_16x16x32_bf16(kf2, qf, zz, 0, 0, 0);
    f32x4 s3 = __builtin_amdgcn_mfma_f32_16x16x32_bf16(kf3, qf, zz, 0, 0, 0);

    float p[16];
    #pragma unroll
    for (int r = 0; r < 4; ++r) {
      p[r] = s0[r]; p[4 + r] = s1[r]; p[8 + r] = s2[r]; p[12 + r] = s3[r];
    }
    float pmax = p[0];
    #pragma unroll
    for (int i = 1; i < 16; ++i) pmax = fmaxf(pmax, p[i]);
    pmax = fmaxf(pmax, __shfl_xor(pmax, 16, 64));
    pmax = fmaxf(pmax, __shfl_xor(pmax, 32, 64));
    float mn = fmaxf(m, pmax);
    float corr = exp2f(m - mn);
    m = mn;
    float lsum = 0.f;
    #pragma unroll
    for (int i = 0; i < 16; ++i) { p[i] = exp2f(p[i] - mn); lsum += p[i]; }
    lsum += __shfl_xor(lsum, 16, 64);
    lsum += __shfl_xor(lsum, 32, 64);
    l = l * corr + lsum;
    #pragma unroll
    for (int r = 0; r < 4; ++r) { ot0[r] *= corr; ot1[r] *= corr; }

    short8 b0, b1;
    #pragma unroll
    for (int i = 0; i < 8; ++i) {
      b0[i] = (short)f2bf(p[i]);
      b1[i] = (short)f2bf(p[8 + i]);
    }
    ot0 = __builtin_amdgcn_mfma_f32_16x16x32_bf16(v00, b0, ot0, 0, 0, 0);
    ot1 = __builtin_amdgcn_mfma_f32_16x16x32_bf16(v01, b0, ot1, 0, 0, 0);
    ot0 = __builtin_amdgcn_mfma_f32_16x16x32_bf16(v10, b1, ot0, 0, 0, 0);
    ot1 = __builtin_amdgcn_mfma_f32_16x16x32_bf16(v11, b1, ot1, 0, 0, 0);
  }

  float inv = 1.0f / l;
  int b = bh >> 3, h = bh & 7;
  ushort* op = ob + ((size_t)(b * N_ + qbase + q_)) * 256 + h * 32;
  #pragma unroll
  for (int r = 0; r < 4; ++r) {
    op[(g << 2) + r]      = f2bf(ot0[r] * inv);
    op[16 + (g << 2) + r] = f2bf(ot1[r] * inv);
  }
}

// ============ K5: O-proj GEMM + bias + residual + LN -> xs f32, xmn bf16 ====
__global__ __launch_bounds__(64) void k_oproj(
    const ushort* __restrict__ ob, const ushort* __restrict__ wot,
    const float* __restrict__ bo, const float* __restrict__ lng,
    const float* __restrict__ lnb, float* __restrict__ xs,
    ushort* __restrict__ xmn) {
  int l = threadIdx.x; int m15 = l & 15, g = l >> 4;
  int ts0 = blockIdx.x * 16;
  f32x4 acc[8];
  #pragma unroll
  for (int nt = 0; nt < 8; ++nt) {
    float init = bo[nt * 16 + m15];
    acc[nt] = (f32x4){init, init, init, init};
  }
  const ushort* oa = ob + (size_t)(ts0 + m15) * 256;
  #pragma unroll 4
  for (int ks = 0; ks < 8; ++ks) {
    short8 af = *(const short8*)(oa + ks * 32 + g * 8);
    #pragma unroll
    for (int nt = 0; nt < 8; ++nt) {
      short8 bfr = *(const short8*)(wot + (size_t)(nt * 16 + m15) * 256 + ks * 32 + g * 8);
      acc[nt] = __builtin_amdgcn_mfma_f32_16x16x32_bf16(af, bfr, acc[nt], 0, 0, 0);
    }
  }
  // add residual, then LN
  #pragma unroll
  for (int nt = 0; nt < 8; ++nt) {
    int c = nt * 16 + m15;
    #pragma unroll
    for (int r = 0; r < 4; ++r)
      acc[nt][r] += xs[(size_t)(ts0 + 4 * g + r) * 128 + c];
  }
  float sum[4] = {0.f, 0.f, 0.f, 0.f}, ssq[4] = {0.f, 0.f, 0.f, 0.f};
  #pragma unroll
  for (int nt = 0; nt < 8; ++nt)
    #pragma unroll
    for (int r = 0; r < 4; ++r) { float v = acc[nt][r]; sum[r] += v; ssq[r] += v * v; }
  #pragma unroll
  for (int mask = 1; mask < 16; mask <<= 1)
    #pragma unroll
    for (int r = 0; r < 4; ++r) {
      sum[r] += __shfl_xor(sum[r], mask, 64);
      ssq[r] += __shfl_xor(ssq[r], mask, 64);
    }
  float mean[4], rstd[4];
  #pragma unroll
  for (int r = 0; r < 4; ++r) {
    mean[r] = sum[r] * (1.0f / 128.0f);
    float var = ssq[r] * (1.0f / 128.0f) - mean[r] * mean[r];
    rstd[r] = rsqrtf(var + 1e-5f);
  }
  #pragma unroll
  for (int nt = 0; nt < 8; ++nt) {
    int c = nt * 16 + m15;
    float ga = lng[c], be = lnb[c];
    #pragma unroll
    for (int r = 0; r < 4; ++r) {
      int ts = ts0 + 4 * g + r;
      float v = acc[nt][r];
      xs[(size_t)ts * 128 + c] = v;
      xmn[(size_t)ts * 128 + c] = f2bf((v - mean[r]) * rstd[r] * ga + be);
    }
  }
}

// ============ K6: MLP GEMM1: xmn @ W1 -> GELU -> hm bf16 ====================
__global__ __launch_bounds__(64) void k_mlp1(
    const ushort* __restrict__ xmn, const ushort* __restrict__ w1t,
    const float* __restrict__ b1, ushort* __restrict__ hm) {
  int l = threadIdx.x; int m15 = l & 15, g = l >> 4;
  int ts0 = blockIdx.x * 16;
  int c0 = blockIdx.y * 128 + m15;
  f32x4 acc[8];
  #pragma unroll
  for (int nt = 0; nt < 8; ++nt) {
    float init = b1[c0 + nt * 16];
    acc[nt] = (f32x4){init, init, init, init};
  }
  const ushort* xa = xmn + (size_t)(ts0 + m15) * 128;
  #pragma unroll
  for (int ks = 0; ks < 4; ++ks) {
    short8 af = *(const short8*)(xa + ks * 32 + g * 8);
    #pragma unroll
    for (int nt = 0; nt < 8; ++nt) {
      short8 bfr = *(const short8*)(w1t + (size_t)(c0 + nt * 16) * 128 + ks * 32 + g * 8);
      acc[nt] = __builtin_amdgcn_mfma_f32_16x16x32_bf16(af, bfr, acc[nt], 0, 0, 0);
    }
  }
  #pragma unroll
  for (int nt = 0; nt < 8; ++nt) {
    int c = c0 + nt * 16;
    #pragma unroll
    for (int r = 0; r < 4; ++r) {
      float v = acc[nt][r];
      v = 0.5f * v * (1.0f + erff(v * 0.70710678118654752f));
      hm[(size_t)(ts0 + 4 * g + r) * 512 + c] = f2bf(v);
    }
  }
}

// ============ K7: MLP GEMM2 + bias + residual -> xs f32 =====================
__global__ __launch_bounds__(64) void k_mlp2(
    const ushort* __restrict__ hm, const ushort* __restrict__ w2t,
    const float* __restrict__ b2, float* __restrict__ xs) {
  int l = threadIdx.x; int m15 = l & 15, g = l >> 4;
  int ts0 = blockIdx.x * 16;
  f32x4 acc[8];
  #pragma unroll
  for (int nt = 0; nt < 8; ++nt) {
    float init = b2[nt * 16 + m15];
    acc[nt] = (f32x4){init, init, init, init};
  }
  const ushort* ha = hm + (size_t)(ts0 + m15) * 512;
  #pragma unroll 4
  for (int ks = 0; ks < 16; ++ks) {
    short8 af = *(const short8*)(ha + ks * 32 + g * 8);
    #pragma unroll
    for (int nt = 0; nt < 8; ++nt) {
      short8 bfr = *(const short8*)(w2t + (size_t)(nt * 16 + m15) * 512 + ks * 32 + g * 8);
      acc[nt] = __builtin_amdgcn_mfma_f32_16x16x32_bf16(af, bfr, acc[nt], 0, 0, 0);
    }
  }
  #pragma unroll
  for (int nt = 0; nt < 8; ++nt) {
    int c = nt * 16 + m15;
    #pragma unroll
    for (int r = 0; r < 4; ++r) {
      size_t a = (size_t)(ts0 + 4 * g + r) * 128 + c;
      xs[a] = acc[nt][r] + xs[a];
    }
  }
}

// ============ K8: final transpose to (B,C,T,H,W) via LDS tiles ==============
__global__ __launch_bounds__(256) void k_out(
    const float* __restrict__ xs, float* __restrict__ out) {
  __shared__ float tile[64][129];
  int bid = blockIdx.x;               // b(2) x t(16) x hwc(4)
  int hwc = bid & 3, t = (bid >> 2) & 15, b = bid >> 6;
  int tid = threadIdx.x;
  #pragma unroll
  for (int i = 0; i < 32; ++i) {
    int idx = i * 256 + tid;
    int hwl = idx >> 7, c = idx & 127;
    tile[hwl][c] = xs[((size_t)b * 4096 + (hwc * 64 + hwl) * 16 + t) * 128 + c];
  }
  __syncthreads();
  #pragma unroll
  for (int i = 0; i < 32; ++i) {
    int idx = i * 256 + tid;
    int c = idx >> 6, hwl = idx & 63;
    out[((size_t)(b * 128 + c) * 16 + t) * 256 + hwc * 64 + hwl] = tile[hwl][c];
  }
}

extern "C" void kernel_launch(void* const* d_in, const int* in_sizes, int n_in,
                              void* d_out, int out_size, void* d_ws, size_t ws_size,
                              hipStream_t stream) {
  const float* x    = (const float*)d_in[0];
  const float* fidx = (const float*)d_in[1];
  const float* fw1  = (const float*)d_in[2];
  const float* fb1  = (const float*)d_in[3];
  const float* fw2  = (const float*)d_in[4];
  const float* fb2  = (const float*)d_in[5];
  const float* ag   = (const float*)d_in[6];
  const float* ab   = (const float*)d_in[7];
  const float* wq   = (const float*)d_in[8];
  const float* wk   = (const float*)d_in[9];
  const float* wv   = (const float*)d_in[10];
  const float* wo   = (const float*)d_in[11];
  const float* bo   = (const float*)d_in[12];
  const float* ng   = (const float*)d_in[13];
  const float* nb   = (const float*)d_in[14];
  const float* mw1  = (const float*)d_in[15];
  const float* mb1  = (const float*)d_in[16];
  const float* mw2  = (const float*)d_in[17];
  const float* mb2  = (const float*)d_in[18];
  float* out = (float*)d_out;

  char* base = (char*)d_ws;
  float*  xs  = (float*) (base);                     // 4 MiB
  ushort* xsn = (ushort*)(base + (4  << 20));        // 2 MiB
  ushort* xmn = (ushort*)(base + (6  << 20));        // 2 MiB
  ushort* qg  = (ushort*)(base + (8  << 20));        // 4 MiB
  ushort* kgb = (ushort*)(base + (12 << 20));        // 4 MiB
  ushort* vt  = (ushort*)(base + (16 << 20));        // 4 MiB
  ushort* obf = (ushort*)(base + (20 << 20));        // 4 MiB
  ushort* hf  = (ushort*)(base + (24 << 20));        // 8 MiB (aliased: hm)
  ushort* hm  = hf;                                  // hf dead before mlp1
  char* wbase = base + (32 << 20);
  ushort* w1t_f = (ushort*)(wbase);
  ushort* w2t_f = (ushort*)(wbase + 131072);
  ushort* wqkvt = (ushort*)(wbase + 262144);
  ushort* wot   = (ushort*)(wbase + 458752);
  ushort* w1t_m = (ushort*)(wbase + 524288);
  ushort* w2t_m = (ushort*)(wbase + 655360);
  float*  w1fr  = (float*) (wbase + 786432);         // total ~33 MiB

  k_prep   <<<1540, 256, 0, stream>>>(fw1, fw2, wq, wk, wv, wo, mw1, mw2,
                                      w1t_f, w2t_f, wqkvt, wot, w1t_m, w2t_m, w1fr);
  k_fusion1<<<dim3(512, 4), 64, 0, stream>>>(x, fidx, w1t_f, w1fr, fb1, hf);
  k_fusion2<<<512, 64, 0, stream>>>(hf, w2t_f, fb2, ag, ab, xs, xsn);
  k_qkv    <<<dim3(512, 6), 64, 0, stream>>>(xsn, wqkvt, qg, kgb, vt);
  k_attn   <<<1024, 256, 0, stream>>>(qg, kgb, vt, obf);
  k_oproj  <<<512, 64, 0, stream>>>(obf, wot, bo, ng, nb, xs, xmn);
  k_mlp1   <<<dim3(512, 4), 64, 0, stream>>>(xmn, w1t_m, mb1, hm);
  k_mlp2   <<<512, 64, 0, stream>>>(hm, w2t_m, mb2, xs);
  k_out    <<<128, 256, 0, stream>>>(xs, out);
}